// Round 2
// baseline (169.003 us; speedup 1.0000x reference)
//
#include <hip/hip_runtime.h>
#include <hip/hip_bf16.h>

#define B_ 64
#define L_ 512
#define H_ 1024
#define EPS_ 1e-13f

typedef unsigned short u16;
typedef __attribute__((ext_vector_type(8))) short s16x8;
typedef __attribute__((ext_vector_type(4))) float f32x4;

__device__ __forceinline__ float bf2f(u16 u) {
  union { unsigned u; float f; } c; c.u = ((unsigned)u) << 16; return c.f;
}
__device__ __forceinline__ u16 f2bf(float f) {
  __hip_bfloat16 h = __float2bfloat16(f);
  union { __hip_bfloat16 h; u16 u; } c; c.h = h; return c.u;
}

// ---- Kernel 0: detect whether device buffers are f32 (flag=1) or bf16 (flag=0) ----
// bf16 N(0,1) data: all u16s have exponent in [96,150]. f32 data read as u16
// pairs: odd u16s sane, even u16s random mantissa bits (~21% sane) -> ~78/128.
__global__ void detect_dtype(const u16* __restrict__ s, int* __restrict__ flag) {
  if (threadIdx.x == 0 && blockIdx.x == 0) {
    int sane = 0;
    for (int i = 0; i < 128; ++i) {
      unsigned e = (s[i] >> 7) & 0xFF;
      sane += (e >= 96 && e <= 150) ? 1 : 0;
    }
    *flag = (sane < 120) ? 1 : 0;  // 1 = f32 buffers, 0 = bf16 buffers
  }
}

// ---- Kernel 1: row softmax + mask renorm -> W (bf16, in ws) ----
template <int F32>
__global__ __launch_bounds__(64) void softmax_rows(const void* __restrict__ attv,
                                                   const void* __restrict__ maskv,
                                                   u16* __restrict__ Wout,
                                                   const int* __restrict__ flag) {
  if (*flag != F32) return;
  const int row = blockIdx.x;
  const int l = threadIdx.x;
  const size_t base = (size_t)row * L_;

  float a[8];
  if (F32) {
    const float* att = (const float*)attv;
    float4 v0 = *(const float4*)(att + base + l * 8);
    float4 v1 = *(const float4*)(att + base + l * 8 + 4);
    a[0] = v0.x; a[1] = v0.y; a[2] = v0.z; a[3] = v0.w;
    a[4] = v1.x; a[5] = v1.y; a[6] = v1.z; a[7] = v1.w;
  } else {
    const u16* att = (const u16*)attv;
    uint4 v = *(const uint4*)(att + base + l * 8);
    const u16* pv = (const u16*)&v;
#pragma unroll
    for (int j = 0; j < 8; ++j) a[j] = bf2f(pv[j]);
  }

  float m = a[0];
#pragma unroll
  for (int j = 1; j < 8; ++j) m = fmaxf(m, a[j]);
#pragma unroll
  for (int off = 32; off > 0; off >>= 1) m = fmaxf(m, __shfl_xor(m, off));

  float e[8], z = 0.f;
#pragma unroll
  for (int j = 0; j < 8; ++j) { e[j] = __expf(a[j] - m); z += e[j]; }
#pragma unroll
  for (int off = 32; off > 0; off >>= 1) z += __shfl_xor(z, off);

  const float invz = 1.0f / z;
  float s2 = 0.f;
#pragma unroll
  for (int j = 0; j < 8; ++j) { e[j] *= invz; s2 += e[j]; }
#pragma unroll
  for (int off = 32; off > 0; off >>= 1) s2 += __shfl_xor(s2, off);

  const float mk = F32 ? ((const float*)maskv)[row] : bf2f(((const u16*)maskv)[row]);
  const float c = mk / (mk * s2 + EPS_);

  union { u16 u[8]; uint4 v; } w;
#pragma unroll
  for (int j = 0; j < 8; ++j) w.u[j] = f2bf(e[j] * c);
  *(uint4*)(Wout + base + l * 8) = w.v;
}

// ---- Kernel 2: transpose X[b, l, h_base+h'] -> XT_chunk[b, h', l] (bf16) ----
template <int F32>
__global__ __launch_bounds__(256) void transpose_x(const void* __restrict__ Xv,
                                                   u16* __restrict__ XT,
                                                   int h_base, int nHt,
                                                   const int* __restrict__ flag) {
  if (*flag != F32) return;
  const int bid = blockIdx.x;
  const int lt = bid & 7;                 // L/64 = 8 tiles
  const int ht = (bid >> 3) % nHt;        // Hc/64 tiles
  const int b  = (bid >> 3) / nHt;
  const int l0 = lt * 64, h0 = ht * 64;
  const int Hc = nHt * 64;

  __shared__ __align__(16) u16 tile[64 * 64];
  const int t = threadIdx.x;
  const int cg = t & 7;
  const int rr = t >> 3;

#pragma unroll
  for (int it = 0; it < 2; ++it) {
    int r = rr + it * 32;
    size_t gidx = ((size_t)(b * L_ + l0 + r)) * H_ + h_base + h0 + cg * 8;
    union { u16 u[8]; uint4 v; } w;
    if (F32) {
      const float* X = (const float*)Xv;
      float4 u0 = *(const float4*)(X + gidx);
      float4 u1 = *(const float4*)(X + gidx + 4);
      w.u[0] = f2bf(u0.x); w.u[1] = f2bf(u0.y); w.u[2] = f2bf(u0.z); w.u[3] = f2bf(u0.w);
      w.u[4] = f2bf(u1.x); w.u[5] = f2bf(u1.y); w.u[6] = f2bf(u1.z); w.u[7] = f2bf(u1.w);
    } else {
      const u16* X = (const u16*)Xv;
      w.v = *(const uint4*)(X + gidx);
    }
    int g = cg ^ (r & 7) ^ ((r >> 3) & 7);
    *(uint4*)&tile[r * 64 + g * 8] = w.v;
  }
  __syncthreads();
#pragma unroll
  for (int it = 0; it < 2; ++it) {
    int hc = rr + it * 32;
    union { u16 u[8]; uint4 v; } e;
#pragma unroll
    for (int m2 = 0; m2 < 8; ++m2) {
      int r = cg * 8 + m2;
      int g = (hc >> 3) ^ (r & 7) ^ ((r >> 3) & 7);
      e.u[m2] = tile[r * 64 + g * 8 + (hc & 7)];
    }
    *(uint4*)(XT + ((size_t)(b * Hc + h0 + hc)) * L_ + l0 + cg * 8) = e.v;
  }
}

// ---- Kernel 3: batched GEMM out = W @ X via XT chunk (B^T layout) ----
template <int F32>
__global__ __launch_bounds__(256) void gemm_bt(const u16* __restrict__ Wm,
                                               const u16* __restrict__ XT,
                                               void* __restrict__ outv,
                                               int h_base, int nNt, int Hc,
                                               const int* __restrict__ flag) {
  if (*flag != F32) return;
  const int K = L_;
  const int bid = blockIdx.x;
  const int nt = bid % nNt;
  const int mt = (bid / nNt) & 3;
  const int b  = bid / (nNt * 4);

  __shared__ __align__(16) u16 lA[128 * 64];
  __shared__ __align__(16) u16 lB[128 * 64];

  const int t = threadIdx.x;
  const int lane = t & 63;
  const int w = t >> 6;
  const int wm = w >> 1, wn = w & 1;

  const u16* gA = Wm + ((size_t)b * L_ + mt * 128) * K;
  const u16* gB = XT + ((size_t)b * Hc + nt * 128) * K;

  f32x4 acc[4][4] = {{{0.f, 0.f, 0.f, 0.f}}};

  const int srow = t >> 3;
  const int sbyte = (t & 7) << 4;

  for (int kt = 0; kt < K; kt += 64) {
#pragma unroll
    for (int q = 0; q < 4; ++q) {
      int r = q * 32 + srow;
      int sc = sbyte ^ ((r & 7) << 4);
      const u16* gpA = gA + (size_t)r * K + kt + (sc >> 1);
      const u16* gpB = gB + (size_t)r * K + kt + (sc >> 1);
      u16* lpA = lA + (size_t)(q * 256 + w * 64) * 8;
      u16* lpB = lB + (size_t)(q * 256 + w * 64) * 8;
      __builtin_amdgcn_global_load_lds((const __attribute__((address_space(1))) unsigned*)gpA,
                                       (__attribute__((address_space(3))) unsigned*)lpA, 16, 0, 0);
      __builtin_amdgcn_global_load_lds((const __attribute__((address_space(1))) unsigned*)gpB,
                                       (__attribute__((address_space(3))) unsigned*)lpB, 16, 0, 0);
    }
    __syncthreads();
#pragma unroll
    for (int ks = 0; ks < 2; ++ks) {
      s16x8 af[4], bfv[4];
#pragma unroll
      for (int mf = 0; mf < 4; ++mf) {
        int r = wm * 64 + mf * 16 + (lane & 15);
        int kb = ks * 64 + ((lane >> 4) << 4);
        af[mf] = *(const s16x8*)((const char*)lA + r * 128 + (kb ^ ((r & 7) << 4)));
      }
#pragma unroll
      for (int nf = 0; nf < 4; ++nf) {
        int r = wn * 64 + nf * 16 + (lane & 15);
        int kb = ks * 64 + ((lane >> 4) << 4);
        bfv[nf] = *(const s16x8*)((const char*)lB + r * 128 + (kb ^ ((r & 7) << 4)));
      }
#pragma unroll
      for (int mf = 0; mf < 4; ++mf)
#pragma unroll
        for (int nf = 0; nf < 4; ++nf)
          acc[mf][nf] = __builtin_amdgcn_mfma_f32_16x16x32_bf16(af[mf], bfv[nf], acc[mf][nf], 0, 0, 0);
    }
    __syncthreads();
  }

  const int orow0 = mt * 128 + wm * 64 + ((lane >> 4) << 2);
  const int ocol0 = h_base + nt * 128 + wn * 64 + (lane & 15);
#pragma unroll
  for (int mf = 0; mf < 4; ++mf)
#pragma unroll
    for (int nf = 0; nf < 4; ++nf)
#pragma unroll
      for (int j = 0; j < 4; ++j) {
        int row = orow0 + mf * 16 + j;
        int col = ocol0 + nf * 16;
        size_t idx = ((size_t)b * L_ + row) * H_ + col;
        if (F32) ((float*)outv)[idx] = acc[mf][nf][j];
        else     ((u16*)outv)[idx] = f2bf(acc[mf][nf][j]);
      }
}

extern "C" void kernel_launch(void* const* d_in, const int* in_sizes, int n_in,
                              void* d_out, int out_size, void* d_ws, size_t ws_size,
                              hipStream_t stream) {
  (void)in_sizes; (void)n_in; (void)out_size;
  const void* sent = d_in[0];  // [B, L, H]
  const void* mask = d_in[1];  // [B, L]
  const void* att  = d_in[2];  // [B, L, L]

  int* flag = (int*)d_ws;
  u16* Wm = (u16*)((char*)d_ws + 64);                      // 32 MiB
  u16* XT = (u16*)((char*)d_ws + 64 + (32ull << 20));      // Hc-chunk of X^T

  detect_dtype<<<1, 64, 0, stream>>>((const u16*)sent, flag);

  const size_t base_need = 64 + (32ull << 20);
  int Hc;
  if (ws_size >= base_need + (64ull << 20))      Hc = 1024;
  else if (ws_size >= base_need + (16ull << 20)) Hc = 256;
  else                                           Hc = 128;
  const int nCh = H_ / Hc;
  const int nHt = Hc / 64;
  const int nNt = Hc / 128;

  for (int f = 0; f < 2; ++f) {
    if (f == 0) softmax_rows<0><<<B_ * L_, 64, 0, stream>>>(att, mask, Wm, flag);
    else        softmax_rows<1><<<B_ * L_, 64, 0, stream>>>(att, mask, Wm, flag);
    for (int c = 0; c < nCh; ++c) {
      int hb = c * Hc;
      if (f == 0) {
        transpose_x<0><<<B_ * nHt * 8, 256, 0, stream>>>(sent, XT, hb, nHt, flag);
        gemm_bt<0><<<B_ * 4 * nNt, 256, 0, stream>>>(Wm, XT, d_out, hb, nNt, Hc, flag);
      } else {
        transpose_x<1><<<B_ * nHt * 8, 256, 0, stream>>>(sent, XT, hb, nHt, flag);
        gemm_bt<1><<<B_ * 4 * nNt, 256, 0, stream>>>(Wm, XT, d_out, hb, nNt, Hc, flag);
      }
    }
  }
}

// Round 3
// 125.123 us; speedup vs baseline: 1.3507x; 1.3507x over previous
//
#include <hip/hip_runtime.h>
#include <hip/hip_bf16.h>

#define B_ 64
#define L_ 512
#define H_ 1024
#define EPS_ 1e-13f

typedef unsigned short u16;
typedef __attribute__((ext_vector_type(8))) short s16x8;
typedef __attribute__((ext_vector_type(4))) float f32x4;

__device__ __forceinline__ u16 f2bf(float f) {
  __hip_bfloat16 h = __float2bfloat16(f);
  union { __hip_bfloat16 h; u16 u; } c; c.h = h; return c.u;
}

// ---- Kernel 1: row softmax + mask renorm -> W (bf16). 4 rows/block, 1 wave/row. ----
__global__ __launch_bounds__(256) void softmax_rows(const float* __restrict__ att,
                                                    const float* __restrict__ mask,
                                                    u16* __restrict__ Wout) {
  const int row = blockIdx.x * 4 + (threadIdx.x >> 6);
  const int l = threadIdx.x & 63;
  const size_t base = (size_t)row * L_;

  float a[8];
  float4 v0 = *(const float4*)(att + base + l * 8);
  float4 v1 = *(const float4*)(att + base + l * 8 + 4);
  a[0] = v0.x; a[1] = v0.y; a[2] = v0.z; a[3] = v0.w;
  a[4] = v1.x; a[5] = v1.y; a[6] = v1.z; a[7] = v1.w;

  float m = a[0];
#pragma unroll
  for (int j = 1; j < 8; ++j) m = fmaxf(m, a[j]);
#pragma unroll
  for (int off = 32; off > 0; off >>= 1) m = fmaxf(m, __shfl_xor(m, off));

  float e[8], z = 0.f;
#pragma unroll
  for (int j = 0; j < 8; ++j) { e[j] = __expf(a[j] - m); z += e[j]; }
#pragma unroll
  for (int off = 32; off > 0; off >>= 1) z += __shfl_xor(z, off);

  const float invz = 1.0f / z;
  float s2 = 0.f;
#pragma unroll
  for (int j = 0; j < 8; ++j) { e[j] *= invz; s2 += e[j]; }
#pragma unroll
  for (int off = 32; off > 0; off >>= 1) s2 += __shfl_xor(s2, off);

  const float mk = mask[row];
  const float c = mk / (mk * s2 + EPS_);

  union { u16 u[8]; uint4 v; } w;
#pragma unroll
  for (int j = 0; j < 8; ++j) w.u[j] = f2bf(e[j] * c);
  *(uint4*)(Wout + base + l * 8) = w.v;
}

// ---- Kernel 2: transpose+convert X f32 [B,L,H] -> XT bf16 [B,H,L] ----
__global__ __launch_bounds__(256) void transpose_x(const float* __restrict__ X,
                                                   u16* __restrict__ XT) {
  const int bid = blockIdx.x;
  const int lt = bid & 7;          // L/64
  const int ht = (bid >> 3) & 15;  // H/64
  const int b  = bid >> 7;
  const int l0 = lt * 64, h0 = ht * 64;

  __shared__ __align__(16) u16 tile[64 * 64];
  const int t = threadIdx.x;
  const int cg = t & 7;
  const int rr = t >> 3;

#pragma unroll
  for (int it = 0; it < 2; ++it) {
    int r = rr + it * 32;
    size_t gidx = ((size_t)(b * L_ + l0 + r)) * H_ + h0 + cg * 8;
    float4 u0 = *(const float4*)(X + gidx);
    float4 u1 = *(const float4*)(X + gidx + 4);
    union { u16 u[8]; uint4 v; } w;
    w.u[0] = f2bf(u0.x); w.u[1] = f2bf(u0.y); w.u[2] = f2bf(u0.z); w.u[3] = f2bf(u0.w);
    w.u[4] = f2bf(u1.x); w.u[5] = f2bf(u1.y); w.u[6] = f2bf(u1.z); w.u[7] = f2bf(u1.w);
    int g = cg ^ (r & 7) ^ ((r >> 3) & 7);
    *(uint4*)&tile[r * 64 + g * 8] = w.v;
  }
  __syncthreads();
#pragma unroll
  for (int it = 0; it < 2; ++it) {
    int hc = rr + it * 32;
    union { u16 u[8]; uint4 v; } e;
#pragma unroll
    for (int m2 = 0; m2 < 8; ++m2) {
      int r = cg * 8 + m2;
      int g = (hc >> 3) ^ (r & 7) ^ ((r >> 3) & 7);
      e.u[m2] = tile[r * 64 + g * 8 + (hc & 7)];
    }
    *(uint4*)(XT + ((size_t)(b * H_ + h0 + hc)) * L_ + l0 + cg * 8) = e.v;
  }
}

// ---- Kernel 3: batched GEMM out = W @ X via XT, 256x256 tile, 8 waves ----
// 2-barrier m97 structure scaled up; XOR-swizzled LDS (linear dest + pre-swizzled
// source for global_load_lds, swizzled ds_read). XCD-swizzled block index.
__global__ __launch_bounds__(512, 2) void gemm_bt(const u16* __restrict__ Wm,
                                                  const u16* __restrict__ XT,
                                                  float* __restrict__ out) {
  // XCD swizzle: grid=512, 512%8==0 -> simple bijective form. 8 blocks of one
  // batch land on one XCD (W+XT panels = 1.5 MB < 4 MB L2).
  const int swz = (blockIdx.x & 7) * 64 + (blockIdx.x >> 3);
  const int b  = swz >> 3;
  const int mt = (swz >> 2) & 1;  // M=512 -> 2 tiles of 256
  const int nt = swz & 3;         // N=1024 -> 4 tiles of 256

  __shared__ __align__(16) u16 lA[256 * 64];
  __shared__ __align__(16) u16 lB[256 * 64];

  const int t = threadIdx.x;
  const int lane = t & 63;
  const int w = t >> 6;           // 8 waves
  const int wm = w >> 2, wn = w & 3;  // 2x4 wave grid, 128x64 per wave

  const u16* gA = Wm + ((size_t)b * L_ + mt * 256) * L_;
  const u16* gB = XT + ((size_t)b * H_ + nt * 256) * L_;

  f32x4 acc[8][4] = {};

  const int srow = t >> 3;         // 0..63 (row within 64-row staging pass)
  const int sbyte = (t & 7) << 4;  // dest byte within 128B row

  for (int kt = 0; kt < L_; kt += 64) {
#pragma unroll
    for (int q = 0; q < 4; ++q) {
      int r = q * 64 + srow;
      int sc = sbyte ^ ((r & 7) << 4);  // inverse-swizzled SOURCE byte
      const u16* gpA = gA + (size_t)r * L_ + kt + (sc >> 1);
      const u16* gpB = gB + (size_t)r * L_ + kt + (sc >> 1);
      char* lpA = (char*)lA + q * 8192 + w * 1024;  // wave-uniform, lane x16B appended by HW
      char* lpB = (char*)lB + q * 8192 + w * 1024;
      __builtin_amdgcn_global_load_lds((const __attribute__((address_space(1))) unsigned*)gpA,
                                       (__attribute__((address_space(3))) unsigned*)lpA, 16, 0, 0);
      __builtin_amdgcn_global_load_lds((const __attribute__((address_space(1))) unsigned*)gpB,
                                       (__attribute__((address_space(3))) unsigned*)lpB, 16, 0, 0);
    }
    __syncthreads();
#pragma unroll
    for (int ks = 0; ks < 2; ++ks) {
      const int kb = ks * 64 + ((lane >> 4) << 4);
      s16x8 af[8], bfv[4];
#pragma unroll
      for (int mf = 0; mf < 8; ++mf) {
        int r = wm * 128 + mf * 16 + (lane & 15);
        af[mf] = *(const s16x8*)((const char*)lA + r * 128 + (kb ^ ((r & 7) << 4)));
      }
#pragma unroll
      for (int nf = 0; nf < 4; ++nf) {
        int r = wn * 64 + nf * 16 + (lane & 15);
        bfv[nf] = *(const s16x8*)((const char*)lB + r * 128 + (kb ^ ((r & 7) << 4)));
      }
#pragma unroll
      for (int mf = 0; mf < 8; ++mf)
#pragma unroll
        for (int nf = 0; nf < 4; ++nf)
          acc[mf][nf] = __builtin_amdgcn_mfma_f32_16x16x32_bf16(af[mf], bfv[nf], acc[mf][nf], 0, 0, 0);
    }
    __syncthreads();
  }

  // C/D layout: col=lane&15, row=(lane>>4)*4+reg  [verified m89/m91]
  const int orow0 = mt * 256 + wm * 128 + ((lane >> 4) << 2);
  const int ocol0 = nt * 256 + wn * 64 + (lane & 15);
#pragma unroll
  for (int mf = 0; mf < 8; ++mf)
#pragma unroll
    for (int nf = 0; nf < 4; ++nf)
#pragma unroll
      for (int j = 0; j < 4; ++j) {
        int row = orow0 + mf * 16 + j;
        int col = ocol0 + nf * 16;
        out[((size_t)b * L_ + row) * H_ + col] = acc[mf][nf][j];
      }
}

extern "C" void kernel_launch(void* const* d_in, const int* in_sizes, int n_in,
                              void* d_out, int out_size, void* d_ws, size_t ws_size,
                              hipStream_t stream) {
  (void)in_sizes; (void)n_in; (void)out_size; (void)ws_size;
  const float* sent = (const float*)d_in[0];  // [B, L, H] f32
  const float* mask = (const float*)d_in[1];  // [B, L]    f32
  const float* att  = (const float*)d_in[2];  // [B, L, L] f32
  u16* Wm = (u16*)d_ws;                          // [B, L, L] bf16 (32 MiB)
  u16* XT = Wm + (size_t)B_ * L_ * L_;           // [B, H, L] bf16 (64 MiB)
  float* outp = (float*)d_out;                   // [B, L, H] f32

  softmax_rows<<<B_ * L_ / 4, 256, 0, stream>>>(att, mask, Wm);
  transpose_x<<<B_ * (H_ / 64) * (L_ / 64), 256, 0, stream>>>(sent, XT);
  gemm_bt<<<B_ * 2 * 4, 512, 0, stream>>>(Wm, XT, outp);
}